// Round 1
// baseline (2869.645 us; speedup 1.0000x reference)
//
#include <hip/hip_runtime.h>
#include <hip/hip_fp16.h>

#define N_B 8
#define P 2048
#define NP (N_B * P)          // 16384
#define EPS 0.1f
#define IEPS 10.0f            // 1/eps
#define LOG_EPS 1e-8f
#define MAX_ITER 50

typedef float f4 __attribute__((ext_vector_type(4)));

// ---------------------------------------------------------------------------
// init: s0 = nu + LOG_EPS  (so a = nu'/s0 == 1, i.e. v=0)
// ---------------------------------------------------------------------------
__global__ __launch_bounds__(256) void k_init(const float* __restrict__ nu,
                                              float* __restrict__ s0) {
    int idx = blockIdx.x * 256 + threadIdx.x;   // grid = NP/256 = 64 blocks
    s0[idx] = nu[idx] + LOG_EPS;
}

// ---------------------------------------------------------------------------
// build K = exp(-C/eps) in fp16 (L3-resident working set: 67 MB)
// ---------------------------------------------------------------------------
__global__ __launch_bounds__(256) void k_build(const float* __restrict__ C,
                                               __half* __restrict__ K) {
    size_t idx = ((size_t)blockIdx.x * 256 + threadIdx.x) * 4;  // grid*256*4 == N*P*P
    float4 c = *(const float4*)(C + idx);
    __half2 h01 = __floats2half2_rn(expf(-IEPS * c.x), expf(-IEPS * c.y));
    __half2 h23 = __floats2half2_rn(expf(-IEPS * c.z), expf(-IEPS * c.w));
    *(__half2*)(K + idx)     = h01;
    *(__half2*)(K + idx + 2) = h23;
}

// ---------------------------------------------------------------------------
// row pass: w_i = mu'_i / sum_j K_ij * a_j,  a_j = nu'_j / sA_j (staged in LDS)
// Also zeroes sB (the next col-pass accumulator) using the first 64 blocks.
// 8 rows per block; each of the 4 waves owns 2 rows -> wave-local reduction only.
// K loads widened to 16 B/lane (dwordx4).
// ---------------------------------------------------------------------------
template <bool USEK>
__global__ __launch_bounds__(256) void k_row(const __half* __restrict__ K,
                                             const float* __restrict__ C,
                                             const float* __restrict__ mu,
                                             const float* __restrict__ nu,
                                             const float* __restrict__ sA,
                                             float* __restrict__ sB,
                                             float* __restrict__ w) {
    __shared__ float a_sh[P];
    const int tid = threadIdx.x;
    if (blockIdx.x < NP / 256) sB[blockIdx.x * 256 + tid] = 0.f;

    const int n  = blockIdx.x >> 8;          // 256 blocks per batch (P/8)
    const int r0 = (blockIdx.x & 255) * 8;
    const float* sAn = sA + n * P;
    const float* nun = nu + n * P;
    #pragma unroll
    for (int j = tid * 4; j < P; j += 1024) {
        f4 nv = *(const f4*)(nun + j);
        f4 sv = *(const f4*)(sAn + j);
        f4 av;
        av.x = (nv.x + LOG_EPS) / sv.x;
        av.y = (nv.y + LOG_EPS) / sv.y;
        av.z = (nv.z + LOG_EPS) / sv.z;
        av.w = (nv.w + LOG_EPS) / sv.w;
        *(f4*)&a_sh[j] = av;
    }
    __syncthreads();

    const int wave = tid >> 6, lane = tid & 63;
    for (int rr = wave; rr < 8; rr += 4) {
        const int i = r0 + rr;
        const size_t rowoff = (size_t)(n * P + i) * P;
        float sum = 0.f;
        #pragma unroll
        for (int jj = 0; jj < P; jj += 512) {
            const int j = jj + lane * 8;
            f4 a0 = *(const f4*)&a_sh[j];
            f4 a1 = *(const f4*)&a_sh[j + 4];
            float k0, k1, k2, k3, k4, k5, k6, k7;
            if (USEK) {
                f4 kv = *(const f4*)(K + rowoff + j);     // 8 halfs, 16B
                const __half2* kh = (const __half2*)&kv;
                float2 f0 = __half22float2(kh[0]);
                float2 f1 = __half22float2(kh[1]);
                float2 f2 = __half22float2(kh[2]);
                float2 f3 = __half22float2(kh[3]);
                k0 = f0.x; k1 = f0.y; k2 = f1.x; k3 = f1.y;
                k4 = f2.x; k5 = f2.y; k6 = f3.x; k7 = f3.y;
            } else {
                f4 c0 = *(const f4*)(C + rowoff + j);
                f4 c1 = *(const f4*)(C + rowoff + j + 4);
                k0 = expf(-IEPS * c0.x); k1 = expf(-IEPS * c0.y);
                k2 = expf(-IEPS * c0.z); k3 = expf(-IEPS * c0.w);
                k4 = expf(-IEPS * c1.x); k5 = expf(-IEPS * c1.y);
                k6 = expf(-IEPS * c1.z); k7 = expf(-IEPS * c1.w);
            }
            sum += k0 * a0.x + k1 * a0.y + k2 * a0.z + k3 * a0.w
                 + k4 * a1.x + k5 * a1.y + k6 * a1.z + k7 * a1.w;
        }
        #pragma unroll
        for (int off = 32; off > 0; off >>= 1) sum += __shfl_down(sum, off, 64);
        if (lane == 0) w[n * P + i] = (mu[n * P + i] + LOG_EPS) / sum;
    }
}

// ---------------------------------------------------------------------------
// col pass: sB_j += sum_i K_ij * w_i  (partial over 32-row chunks, atomicAdd)
// grid = n(8) x rc(64) = 512 blocks; each block covers a full 2048-col stripe,
// 8 adjacent cols per thread -> 16 B/lane loads (one full K row per i-step).
// ---------------------------------------------------------------------------
template <bool USEK>
__global__ __launch_bounds__(256) void k_col(const __half* __restrict__ K,
                                             const float* __restrict__ C,
                                             const float* __restrict__ w,
                                             float* __restrict__ sB) {
    const int RPB = 32;
    int b = blockIdx.x;
    const int rc = b & 63; b >>= 6;
    const int n  = b;
    const int j  = threadIdx.x * 8;
    const int i0 = rc * RPB;
    const float* wn = w + n * P + i0;
    float s[8];
    #pragma unroll
    for (int q = 0; q < 8; ++q) s[q] = 0.f;
    if (USEK) {
        const __half* kp = K + ((size_t)n * P + i0) * P + j;
        #pragma unroll 4
        for (int i = 0; i < RPB; ++i) {
            const float wi = wn[i];
            f4 kv = *(const f4*)kp;                       // 8 halfs, 16B
            const __half2* kh = (const __half2*)&kv;
            float2 f0 = __half22float2(kh[0]);
            float2 f1 = __half22float2(kh[1]);
            float2 f2 = __half22float2(kh[2]);
            float2 f3 = __half22float2(kh[3]);
            s[0] += wi * f0.x; s[1] += wi * f0.y;
            s[2] += wi * f1.x; s[3] += wi * f1.y;
            s[4] += wi * f2.x; s[5] += wi * f2.y;
            s[6] += wi * f3.x; s[7] += wi * f3.y;
            kp += P;
        }
    } else {
        const float* cp = C + ((size_t)n * P + i0) * P + j;
        #pragma unroll 2
        for (int i = 0; i < RPB; ++i) {
            const float wi = wn[i];
            f4 c0 = *(const f4*)(cp);
            f4 c1 = *(const f4*)(cp + 4);
            s[0] += wi * expf(-IEPS * c0.x); s[1] += wi * expf(-IEPS * c0.y);
            s[2] += wi * expf(-IEPS * c0.z); s[3] += wi * expf(-IEPS * c0.w);
            s[4] += wi * expf(-IEPS * c1.x); s[5] += wi * expf(-IEPS * c1.y);
            s[6] += wi * expf(-IEPS * c1.z); s[7] += wi * expf(-IEPS * c1.w);
            cp += P;
        }
    }
    float* sp = sB + n * P + j;
    #pragma unroll
    for (int q = 0; q < 8; ++q) atomicAdd(sp + q, s[q]);
}

// ---------------------------------------------------------------------------
// a = nu'/s  (precomputed once before the final pass; written into dead s1)
// ---------------------------------------------------------------------------
__global__ __launch_bounds__(256) void k_a(const float* __restrict__ nu,
                                           const float* __restrict__ s,
                                           float* __restrict__ a) {
    int idx = blockIdx.x * 256 + threadIdx.x;   // grid = NP/256
    a[idx] = (nu[idx] + LOG_EPS) / s[idx];
}

// ---------------------------------------------------------------------------
// final: pi = w_i * a_j * exp(-C/eps) (fp32 C), write pi + C copy,
// per-block cost partial -> part[g]  (NO global atomics; see k_reduce)
// ---------------------------------------------------------------------------
__global__ __launch_bounds__(256) void k_final(const float* __restrict__ C,
                                               const float* __restrict__ a,
                                               const float* __restrict__ w,
                                               float* __restrict__ part,
                                               float* __restrict__ out) {
    const int g   = blockIdx.x;              // NP blocks, one row each
    const int n   = g >> 11;
    const int tid = threadIdx.x;
    const float wi = w[g];
    const size_t rowoff = (size_t)g * P;
    const float* Crow = C + rowoff;
    const float* an   = a + (size_t)n * P;
    float* pi_out = out + N_B + rowoff;
    float* c_out  = out + N_B + (size_t)NP * P + rowoff;
    float cost = 0.f;
    #pragma unroll
    for (int jj = 0; jj < P; jj += 1024) {
        const int j = jj + tid * 4;
        f4 c4 = *(const f4*)(Crow + j);
        f4 a4 = *(const f4*)(an + j);
        f4 p;
        p.x = wi * a4.x * expf(-IEPS * c4.x);
        p.y = wi * a4.y * expf(-IEPS * c4.y);
        p.z = wi * a4.z * expf(-IEPS * c4.z);
        p.w = wi * a4.w * expf(-IEPS * c4.w);
        __builtin_nontemporal_store(p,  (f4*)(pi_out + j));
        __builtin_nontemporal_store(c4, (f4*)(c_out + j));
        cost += p.x * c4.x + p.y * c4.y + p.z * c4.z + p.w * c4.w;
    }
    const int wave = tid >> 6, lane = tid & 63;
    #pragma unroll
    for (int off = 32; off > 0; off >>= 1) cost += __shfl_down(cost, off, 64);
    __shared__ float red[4];
    if (lane == 0) red[wave] = cost;
    __syncthreads();
    if (tid == 0) part[g] = red[0] + red[1] + red[2] + red[3];
}

// ---------------------------------------------------------------------------
// cost reduce: out[n] = sum of 2048 per-row partials (deterministic, no atomics)
// ---------------------------------------------------------------------------
__global__ __launch_bounds__(256) void k_reduce(const float* __restrict__ part,
                                                float* __restrict__ out) {
    const int n = blockIdx.x, tid = threadIdx.x;
    float s = 0.f;
    for (int b = tid; b < P; b += 256) s += part[(size_t)n * P + b];
    const int wave = tid >> 6, lane = tid & 63;
    #pragma unroll
    for (int off = 32; off > 0; off >>= 1) s += __shfl_down(s, off, 64);
    __shared__ float red[4];
    if (lane == 0) red[wave] = s;
    __syncthreads();
    if (tid == 0) out[n] = red[0] + red[1] + red[2] + red[3];
}

// ---------------------------------------------------------------------------
extern "C" void kernel_launch(void* const* d_in, const int* in_sizes, int n_in,
                              void* d_out, int out_size, void* d_ws, size_t ws_size,
                              hipStream_t stream) {
    const float* C  = (const float*)d_in[0];
    const float* mu = (const float*)d_in[1];
    const float* nu = (const float*)d_in[2];
    float* out = (float*)d_out;

    // ws layout: s0[NP] | s1[NP] | w[NP] | K[N*P*P] (fp16)
    // After the loop: a (=nu'/s0) is written into dead s1; cost partials reuse
    // dead s0 -> no extra workspace vs. the previous version.
    float* s0 = (float*)d_ws;
    float* s1 = s0 + NP;
    float* w  = s1 + NP;
    __half* K = (__half*)(w + NP);
    const size_t needK = 3ull * NP * sizeof(float) + (size_t)NP * P * sizeof(__half);
    const bool useK = (ws_size >= needK);

    k_init<<<NP / 256, 256, 0, stream>>>(nu, s0);
    if (useK) k_build<<<((size_t)NP * P) / 1024, 256, 0, stream>>>(C, K);

    for (int t = 0; t < MAX_ITER; ++t) {
        float* sA = (t & 1) ? s1 : s0;
        float* sB = (t & 1) ? s0 : s1;
        if (useK) {
            k_row<true><<<NP / 8, 256, 0, stream>>>(K, C, mu, nu, sA, sB, w);
            k_col<true><<<N_B * 64, 256, 0, stream>>>(K, C, w, sB);
        } else {
            k_row<false><<<NP / 8, 256, 0, stream>>>(K, C, mu, nu, sA, sB, w);
            k_col<false><<<N_B * 64, 256, 0, stream>>>(K, C, w, sB);
        }
    }
    // last col pass (t=49, odd) wrote s0 -> final a comes from s0.
    float* aBuf = s1;   // s1 is dead after the loop
    float* part = s0;   // s0 is dead after k_a consumed it
    k_a<<<NP / 256, 256, 0, stream>>>(nu, s0, aBuf);
    k_final<<<NP, 256, 0, stream>>>(C, aBuf, w, part, out);
    k_reduce<<<N_B, 256, 0, stream>>>(part, out);
}

// Round 2
// 1628.331 us; speedup vs baseline: 1.7623x; 1.7623x over previous
//
#include <hip/hip_runtime.h>
#include <hip/hip_fp16.h>

#define N_B 8
#define P 2048
#define NP (N_B * P)          // 16384
#define EPS 0.1f
#define IEPS 10.0f            // 1/eps
#define LOG_EPS 1e-8f
#define MAX_ITER 50

typedef float f4 __attribute__((ext_vector_type(4)));

// ---------------------------------------------------------------------------
// init: s0 = nu + LOG_EPS  (so a = nu'/s0 == 1, i.e. v=0)
// ---------------------------------------------------------------------------
__global__ __launch_bounds__(256) void k_init(const float* __restrict__ nu,
                                              float* __restrict__ s0) {
    int idx = blockIdx.x * 256 + threadIdx.x;   // grid = NP/256 = 64 blocks
    s0[idx] = nu[idx] + LOG_EPS;
}

// ---------------------------------------------------------------------------
// build K = exp(-C/eps) fp16 (fallback tier: K only)
// ---------------------------------------------------------------------------
__global__ __launch_bounds__(256) void k_build(const float* __restrict__ C,
                                               __half* __restrict__ K) {
    size_t idx = ((size_t)blockIdx.x * 256 + threadIdx.x) * 4;
    float4 c = *(const float4*)(C + idx);
    __half2 h01 = __floats2half2_rn(expf(-IEPS * c.x), expf(-IEPS * c.y));
    __half2 h23 = __floats2half2_rn(expf(-IEPS * c.z), expf(-IEPS * c.w));
    *(__half2*)(K + idx)     = h01;
    *(__half2*)(K + idx + 2) = h23;
}

// ---------------------------------------------------------------------------
// build K AND K^T in fp16, 64x64 tiles via LDS (one-time, ~50 us)
// grid = N_B * 32 * 32 blocks, 256 threads
// ---------------------------------------------------------------------------
__global__ __launch_bounds__(256) void k_build2(const float* __restrict__ C,
                                                __half* __restrict__ K,
                                                __half* __restrict__ KT) {
    __shared__ __half sh[64][72];            // +8 halfs pad breaks bank stride
    int b = blockIdx.x;
    const int tj = b & 31; b >>= 5;
    const int ti = b & 31; b >>= 5;
    const int n  = b;
    const int tid = threadIdx.x;
    const int lr = tid >> 4;                 // 0..15
    const int lc = (tid & 15) * 4;           // 0,4,...,60
    #pragma unroll
    for (int e = 0; e < 4; ++e) {
        const int r = e * 16 + lr;
        const size_t off = ((size_t)(n * P + ti * 64 + r)) * P + tj * 64 + lc;
        f4 c4 = *(const f4*)(C + off);
        __half h0 = __float2half(expf(-IEPS * c4.x));
        __half h1 = __float2half(expf(-IEPS * c4.y));
        __half h2 = __float2half(expf(-IEPS * c4.z));
        __half h3 = __float2half(expf(-IEPS * c4.w));
        *(__half2*)(K + off)     = __halves2half2(h0, h1);
        *(__half2*)(K + off + 2) = __halves2half2(h2, h3);
        sh[r][lc] = h0; sh[r][lc + 1] = h1; sh[r][lc + 2] = h2; sh[r][lc + 3] = h3;
    }
    __syncthreads();
    #pragma unroll
    for (int e = 0; e < 4; ++e) {
        const int r = e * 16 + lr;           // KT row within tile = original col
        const size_t off = ((size_t)(n * P + tj * 64 + r)) * P + ti * 64 + lc;
        *(__half2*)(KT + off)     = __halves2half2(sh[lc][r],     sh[lc + 1][r]);
        *(__half2*)(KT + off + 2) = __halves2half2(sh[lc + 2][r], sh[lc + 3][r]);
    }
}

// ---------------------------------------------------------------------------
// symmetric streaming pass over a row-major fp16 matrix (K or K^T).
// PASS=0 (row): vin=sA, stage a_j=nu'_j/sA_j, out w_i = mu'_i / (K a)_i
// PASS=1 (col): vin=w,  stage w_j directly,   out sB_i = (K^T w)_i  (no atomics)
// 8 matrix-rows per block, 2 per wave; vector register-cached (32 f32/lane),
// no LDS, no barriers; K loads 16 B/lane coalesced.
// ---------------------------------------------------------------------------
template <int PASS>
__global__ __launch_bounds__(256) void k_pass(const __half* __restrict__ Km,
                                              const float* __restrict__ mu,
                                              const float* __restrict__ nu,
                                              const float* __restrict__ vin,
                                              float* __restrict__ vout) {
    const int tid  = threadIdx.x;
    const int n    = blockIdx.x >> 8;        // 256 blocks per batch (P/8)
    const int r0   = (blockIdx.x & 255) * 8;
    const int wave = tid >> 6, lane = tid & 63;
    const float* vn  = vin + n * P;
    const float* nun = nu  + n * P;

    f4 areg[8];
    #pragma unroll
    for (int q = 0; q < 4; ++q) {
        const int j = q * 512 + lane * 8;
        f4 sv0 = *(const f4*)(vn + j);
        f4 sv1 = *(const f4*)(vn + j + 4);
        if (PASS == 0) {
            f4 nv0 = *(const f4*)(nun + j);
            f4 nv1 = *(const f4*)(nun + j + 4);
            f4 a0, a1;
            a0.x = (nv0.x + LOG_EPS) / sv0.x;
            a0.y = (nv0.y + LOG_EPS) / sv0.y;
            a0.z = (nv0.z + LOG_EPS) / sv0.z;
            a0.w = (nv0.w + LOG_EPS) / sv0.w;
            a1.x = (nv1.x + LOG_EPS) / sv1.x;
            a1.y = (nv1.y + LOG_EPS) / sv1.y;
            a1.z = (nv1.z + LOG_EPS) / sv1.z;
            a1.w = (nv1.w + LOG_EPS) / sv1.w;
            areg[2 * q] = a0; areg[2 * q + 1] = a1;
        } else {
            areg[2 * q] = sv0; areg[2 * q + 1] = sv1;
        }
    }

    #pragma unroll
    for (int rp = 0; rp < 2; ++rp) {
        const int i = r0 + wave + rp * 4;
        const size_t rowoff = (size_t)(n * P + i) * P;
        float sa = 0.f, sb = 0.f;
        #pragma unroll
        for (int q = 0; q < 4; ++q) {
            const int j = q * 512 + lane * 8;
            f4 kv = *(const f4*)(Km + rowoff + j);   // 8 halfs, 16 B
            const __half2* kh = (const __half2*)&kv;
            float2 f0 = __half22float2(kh[0]);
            float2 f1 = __half22float2(kh[1]);
            float2 f2 = __half22float2(kh[2]);
            float2 f3 = __half22float2(kh[3]);
            f4 a0 = areg[2 * q], a1 = areg[2 * q + 1];
            sa += f0.x * a0.x + f0.y * a0.y + f1.x * a0.z + f1.y * a0.w;
            sb += f2.x * a1.x + f2.y * a1.y + f3.x * a1.z + f3.y * a1.w;
        }
        float sum = sa + sb;
        #pragma unroll
        for (int off = 32; off > 0; off >>= 1) sum += __shfl_down(sum, off, 64);
        if (lane == 0) {
            if (PASS == 0) vout[n * P + i] = (mu[n * P + i] + LOG_EPS) / sum;
            else           vout[n * P + i] = sum;
        }
    }
}

// ---------------------------------------------------------------------------
// FALLBACK (ws too small for K^T): round-0 proven row/col kernels
// ---------------------------------------------------------------------------
template <bool USEK>
__global__ __launch_bounds__(256) void k_row(const __half* __restrict__ K,
                                             const float* __restrict__ C,
                                             const float* __restrict__ mu,
                                             const float* __restrict__ nu,
                                             const float* __restrict__ sA,
                                             float* __restrict__ sB,
                                             float* __restrict__ w) {
    __shared__ float a_sh[P];
    const int tid = threadIdx.x;
    if (blockIdx.x < NP / 256) sB[blockIdx.x * 256 + tid] = 0.f;

    const int n  = blockIdx.x >> 8;
    const int r0 = (blockIdx.x & 255) * 8;
    const float* sAn = sA + n * P;
    const float* nun = nu + n * P;
    for (int j = tid; j < P; j += 256)
        a_sh[j] = (nun[j] + LOG_EPS) / sAn[j];
    __syncthreads();

    const int wave = tid >> 6, lane = tid & 63;
    for (int rr = wave; rr < 8; rr += 4) {
        const int i = r0 + rr;
        const size_t rowoff = (size_t)(n * P + i) * P;
        float sum = 0.f;
        #pragma unroll
        for (int jj = 0; jj < P; jj += 256) {
            const int j = jj + lane * 4;
            float4 av = *(const float4*)&a_sh[j];
            float k0, k1, k2, k3;
            if (USEK) {
                const __half2* kp = (const __half2*)(K + rowoff + j);
                float2 f01 = __half22float2(kp[0]);
                float2 f23 = __half22float2(kp[1]);
                k0 = f01.x; k1 = f01.y; k2 = f23.x; k3 = f23.y;
            } else {
                float4 c4 = *(const float4*)(C + rowoff + j);
                k0 = expf(-IEPS * c4.x); k1 = expf(-IEPS * c4.y);
                k2 = expf(-IEPS * c4.z); k3 = expf(-IEPS * c4.w);
            }
            sum += k0 * av.x + k1 * av.y + k2 * av.z + k3 * av.w;
        }
        #pragma unroll
        for (int off = 32; off > 0; off >>= 1) sum += __shfl_down(sum, off, 64);
        if (lane == 0) w[n * P + i] = (mu[n * P + i] + LOG_EPS) / sum;
    }
}

template <bool USEK>
__global__ __launch_bounds__(256) void k_col(const __half* __restrict__ K,
                                             const float* __restrict__ C,
                                             const float* __restrict__ w,
                                             float* __restrict__ sB) {
    const int RPB = 64;
    int b = blockIdx.x;
    const int rc = b & 31; b >>= 5;
    const int jt = b & 3;  b >>= 2;
    const int n  = b;
    const int j  = jt * 512 + threadIdx.x * 2;
    const int i0 = rc * RPB;
    const float* wn = w + n * P;
    float s0 = 0.f, s1 = 0.f;
    if (USEK) {
        const __half2* kp = (const __half2*)(K + ((size_t)n * P + i0) * P + j);
        #pragma unroll 4
        for (int i = 0; i < RPB; ++i) {
            const float wi = wn[i0 + i];
            float2 kv = __half22float2(*kp);
            s0 += wi * kv.x; s1 += wi * kv.y;
            kp += P / 2;
        }
    } else {
        const float* cp = C + ((size_t)n * P + i0) * P + j;
        #pragma unroll 2
        for (int i = 0; i < RPB; ++i) {
            const float wi = wn[i0 + i];
            s0 += wi * expf(-IEPS * cp[0]);
            s1 += wi * expf(-IEPS * cp[1]);
            cp += P;
        }
    }
    atomicAdd(&sB[n * P + j],     s0);
    atomicAdd(&sB[n * P + j + 1], s1);
}

// ---------------------------------------------------------------------------
// a = nu'/s  (once, before final pass; written into dead s1)
// ---------------------------------------------------------------------------
__global__ __launch_bounds__(256) void k_a(const float* __restrict__ nu,
                                           const float* __restrict__ s,
                                           float* __restrict__ a) {
    int idx = blockIdx.x * 256 + threadIdx.x;
    a[idx] = (nu[idx] + LOG_EPS) / s[idx];
}

// ---------------------------------------------------------------------------
// final: pi = w_i * a_j * exp(-C/eps) (fp32 C), write pi + C copy,
// per-block cost partial -> part[g]  (no global atomics)
// ---------------------------------------------------------------------------
__global__ __launch_bounds__(256) void k_final(const float* __restrict__ C,
                                               const float* __restrict__ a,
                                               const float* __restrict__ w,
                                               float* __restrict__ part,
                                               float* __restrict__ out) {
    const int g   = blockIdx.x;              // NP blocks, one row each
    const int n   = g >> 11;
    const int tid = threadIdx.x;
    const float wi = w[g];
    const size_t rowoff = (size_t)g * P;
    const float* Crow = C + rowoff;
    const float* an   = a + (size_t)n * P;
    float* pi_out = out + N_B + rowoff;
    float* c_out  = out + N_B + (size_t)NP * P + rowoff;
    float cost = 0.f;
    #pragma unroll
    for (int jj = 0; jj < P; jj += 1024) {
        const int j = jj + tid * 4;
        f4 c4 = *(const f4*)(Crow + j);
        f4 a4 = *(const f4*)(an + j);
        f4 p;
        p.x = wi * a4.x * expf(-IEPS * c4.x);
        p.y = wi * a4.y * expf(-IEPS * c4.y);
        p.z = wi * a4.z * expf(-IEPS * c4.z);
        p.w = wi * a4.w * expf(-IEPS * c4.w);
        __builtin_nontemporal_store(p,  (f4*)(pi_out + j));
        __builtin_nontemporal_store(c4, (f4*)(c_out + j));
        cost += p.x * c4.x + p.y * c4.y + p.z * c4.z + p.w * c4.w;
    }
    const int wave = tid >> 6, lane = tid & 63;
    #pragma unroll
    for (int off = 32; off > 0; off >>= 1) cost += __shfl_down(cost, off, 64);
    __shared__ float red[4];
    if (lane == 0) red[wave] = cost;
    __syncthreads();
    if (tid == 0) part[g] = red[0] + red[1] + red[2] + red[3];
}

// ---------------------------------------------------------------------------
// cost reduce: out[n] = sum of 2048 per-row partials (deterministic)
// ---------------------------------------------------------------------------
__global__ __launch_bounds__(256) void k_reduce(const float* __restrict__ part,
                                                float* __restrict__ out) {
    const int n = blockIdx.x, tid = threadIdx.x;
    float s = 0.f;
    for (int b = tid; b < P; b += 256) s += part[(size_t)n * P + b];
    const int wave = tid >> 6, lane = tid & 63;
    #pragma unroll
    for (int off = 32; off > 0; off >>= 1) s += __shfl_down(s, off, 64);
    __shared__ float red[4];
    if (lane == 0) red[wave] = s;
    __syncthreads();
    if (tid == 0) out[n] = red[0] + red[1] + red[2] + red[3];
}

// ---------------------------------------------------------------------------
extern "C" void kernel_launch(void* const* d_in, const int* in_sizes, int n_in,
                              void* d_out, int out_size, void* d_ws, size_t ws_size,
                              hipStream_t stream) {
    const float* C  = (const float*)d_in[0];
    const float* mu = (const float*)d_in[1];
    const float* nu = (const float*)d_in[2];
    float* out = (float*)d_out;

    // ws layout: s0[NP] | s1[NP] | w[NP] | K[N*P*P] fp16 | KT[N*P*P] fp16
    float* s0 = (float*)d_ws;
    float* s1 = s0 + NP;
    float* w  = s1 + NP;
    __half* K  = (__half*)(w + NP);
    __half* KT = K + (size_t)NP * P;
    const size_t base   = 3ull * NP * sizeof(float);
    const size_t needK  = base + (size_t)NP * P * sizeof(__half);
    const size_t needKT = base + 2ull * (size_t)NP * P * sizeof(__half);
    const int tier = (ws_size >= needKT) ? 2 : (ws_size >= needK) ? 1 : 0;

    k_init<<<NP / 256, 256, 0, stream>>>(nu, s0);

    if (tier == 2) {
        k_build2<<<N_B * 32 * 32, 256, 0, stream>>>(C, K, KT);
        for (int t = 0; t < MAX_ITER; ++t) {
            float* sA = (t & 1) ? s1 : s0;
            float* sB = (t & 1) ? s0 : s1;
            k_pass<0><<<NP / 8, 256, 0, stream>>>(K,  mu, nu, sA, w);
            k_pass<1><<<NP / 8, 256, 0, stream>>>(KT, mu, nu, w,  sB);
        }
    } else if (tier == 1) {
        k_build<<<((size_t)NP * P) / 1024, 256, 0, stream>>>(C, K);
        for (int t = 0; t < MAX_ITER; ++t) {
            float* sA = (t & 1) ? s1 : s0;
            float* sB = (t & 1) ? s0 : s1;
            k_row<true><<<NP / 8, 256, 0, stream>>>(K, C, mu, nu, sA, sB, w);
            k_col<true><<<8 * 4 * 32, 256, 0, stream>>>(K, C, w, sB);
        }
    } else {
        for (int t = 0; t < MAX_ITER; ++t) {
            float* sA = (t & 1) ? s1 : s0;
            float* sB = (t & 1) ? s0 : s1;
            k_row<false><<<NP / 8, 256, 0, stream>>>(K, C, mu, nu, sA, sB, w);
            k_col<false><<<8 * 4 * 32, 256, 0, stream>>>(K, C, w, sB);
        }
    }

    // last col pass (t=49, odd) wrote s0 -> final a comes from s0.
    float* aBuf = s1;   // s1 dead after loop
    float* part = s0;   // s0 dead after k_a consumes it
    k_a<<<NP / 256, 256, 0, stream>>>(nu, s0, aBuf);
    k_final<<<NP, 256, 0, stream>>>(C, aBuf, w, part, out);
    k_reduce<<<N_B, 256, 0, stream>>>(part, out);
}